// Round 5
// baseline (8048.981 us; speedup 1.0000x reference)
//
#include <hip/hip_runtime.h>
#include <stdint.h>
#include <math.h>
#include <type_traits>

// ---- problem constants ----
constexpr int HD   = 512;    // hidden/embed dim
constexpr int TS   = 256;    // sequence length
constexpr int NB   = 64;     // batch per direction
constexpr int MBR  = 128;    // fwd+rev batched rows
constexpr int SLAB = MBR * HD;  // 65536 elements per h-slab

typedef __attribute__((ext_vector_type(8))) short bf16x8;
typedef __attribute__((ext_vector_type(4))) float f32x4;

__device__ __forceinline__ unsigned short f2bf(float f){
  union { float f; unsigned u; } v; v.f = f;
  unsigned r = v.u + 0x7fffu + ((v.u >> 16) & 1u);
  return (unsigned short)(r >> 16);
}
__device__ __forceinline__ float fsig(float x){ return 1.f / (1.f + __expf(-x)); }
__device__ __forceinline__ float ftanh(float x){ return 1.f - 2.f / (__expf(2.f * x) + 1.f); }
__device__ __forceinline__ void vdrain(){ asm volatile("s_waitcnt vmcnt(0)" ::: "memory"); }

// Wc[n][k] bf16 (row-major [2048][1024]): k<512 -> Wih[n][k], k>=512 -> Whh[n][k-512]
__global__ void prep_w(const float* __restrict__ Wih, const float* __restrict__ Whh,
                       unsigned short* __restrict__ Wc){
  int idx = blockIdx.x * 256 + threadIdx.x;
  int n = idx >> 10;
  int k = idx & 1023;
  float v = (k < HD) ? Wih[n * HD + k] : Whh[n * HD + (k - HD)];
  Wc[idx] = f2bf(v);
}

__global__ void prep_bias(const float* __restrict__ a, const float* __restrict__ b,
                          float* __restrict__ o){
  int i = blockIdx.x * 256 + threadIdx.x;
  if (i < 2048) o[i] = a[i] + b[i];
}

// Xp[t][row][k] bf16: row<64: text[row][t][k]; row>=64: text[row-64][TS-1-t][k]
__global__ void pack_x(const float* __restrict__ text, unsigned short* __restrict__ Xp){
  int idx = blockIdx.x * 256 + threadIdx.x;   // TS*MBR*HD = 16,777,216
  int k   = idx & 511;
  int row = (idx >> 9) & 127;
  int t   = idx >> 16;
  int b   = row & 63;
  int tt  = (row < 64) ? t : (TS - 1 - t);
  Xp[idx] = f2bf(text[((size_t)b * TS + tt) * HD + k]);
}

// Persistent pipelined 2-layer LSTM. Fence-free dataflow sync:
// mutable shared data (h slabs, flags) moves via relaxed agent-scope atomics
// (sc1, L2-bypass -> coherence point); read-only data (Xp, weights) stays
// normally cached. NO buffer_wbl2 / buffer_inv per step.
// Grid: 256 WGs x 512 threads, 1 WG/CU, 128 KB LDS.
// WG wg: layer = wg>>7; wl = wg&127; grp = wl>>5 (32 batch rows); slice = wl&31 (16 units).
// Flags F[0..127]: L0 (grp*32+slice) = steps completed.  F[128..255]: same for L1.
__global__ __launch_bounds__(512, 1)
void lstm_persist(const unsigned short* __restrict__ Xp,
                  const unsigned short* __restrict__ Wc,   // [2][2048][1024] bf16
                  const float* __restrict__ bias,          // [2][2048]
                  unsigned short* __restrict__ h0r,        // [16][128][512] bf16 ring
                  unsigned short* __restrict__ h1r,        // [2][128][512] bf16 ring
                  float* __restrict__ H1f,                 // [128][512] fp32 (final h1)
                  int* __restrict__ F)                     // [256] flags
{
  extern __shared__ unsigned short Blds[];   // 64 cols x 1024 k, XOR-swizzled, 128 KB

  const int wg    = blockIdx.x;
  const int layer = wg >> 7;
  const int wl    = wg & 127;
  const int grp   = wl >> 5;
  const int slice = wl & 31;
  const int m0    = grp * 32;
  const int u0    = slice * 16;
  const int tid   = threadIdx.x;
  const int wv    = tid >> 6;
  const int l     = tid & 63;
  const int lj    = l & 15;
  const int lk    = l >> 4;
  const int wgrp  = wv & 3;
  const int mi    = wv >> 2;

  int* F0g = F + grp * 32;          // producer flags: layer 0, this row-group
  int* F1g = F + 128 + grp * 32;    // producer flags: layer 1, this row-group

  // ---- one-time: stage this WG's weight slice into LDS, swizzled ----
  const unsigned short* Wcl = Wc + (size_t)layer * 2048 * 1024;
  for (int it = tid; it < 64 * 128; it += 512){
    int c  = it >> 7, kg = it & 127;
    int unit = u0 + ((c >> 4) << 2) + ((c & 15) >> 2);
    int gate = c & 3;
    bf16x8 v = *(const bf16x8*)(Wcl + (size_t)(gate * HD + unit) * 1024 + kg * 8);
    *(bf16x8*)((char*)Blds + c * 2048 + ((kg ^ (c & 7)) << 4)) = v;
  }

  const int myunit = u0 + (wgrp << 2) + (lj >> 2);
  const int mygate = lj & 3;
  const float bgv  = bias[layer * 2048 + mygate * HD + myunit];
  const int aoff   = (m0 + mi * 16 + lj) * HD + lk * 8;
  const int cboff  = (wgrp * 16 + lj) * 2048;
  const int swz    = lj & 7;

  float cst[4] = {0.f, 0.f, 0.f, 0.f};
  __syncthreads();   // weights staged

  // 16-MFMA half-K: gb=0 -> input-side weights, gb=64 -> recurrent weights.
  // COH: A-operand from mutable h slabs -> relaxed agent atomic dword loads (sc1).
  auto halfK = [&](const unsigned short* __restrict__ src, int gb, f32x4& acc, auto coh){
    #pragma unroll
    for (int kk = 0; kk < 16; ++kk){
      bf16x8 b = *(const bf16x8*)((const char*)Blds + cboff + (((gb + kk * 4 + lk) ^ swz) << 4));
      bf16x8 a;
      if constexpr (decltype(coh)::value){
        const unsigned* ap = (const unsigned*)(src + aoff + kk * 32);
        union { unsigned u[4]; bf16x8 v; } uu;
        #pragma unroll
        for (int q = 0; q < 4; ++q)
          uu.u[q] = __hip_atomic_load(ap + q, __ATOMIC_RELAXED, __HIP_MEMORY_SCOPE_AGENT);
        a = uu.v;
      } else {
        a = *(const bf16x8*)(src + aoff + kk * 32);
      }
      acc = __builtin_amdgcn_mfma_f32_16x16x32_bf16(a, b, acc, 0, 0, 0);
    }
  };

  // wave-0 poll: lanes 0..31 watch setA>=tA; lanes 32..63 watch setB>=tB.
  // Relaxed loads only; no acquire fence (h reads are sc1, nothing stale cached).
  auto pollwait = [&](const int* setA, int tA, const int* setB, int tB){
    const int* fp = (l < 32) ? (setA + l) : (setB + (l - 32));
    const int tgt = (l < 32) ? tA : tB;
    for (;;){
      int v = __hip_atomic_load(fp, __ATOMIC_RELAXED, __HIP_MEMORY_SCOPE_AGENT);
      if (__all(v >= tgt)) break;
      __builtin_amdgcn_s_sleep(1);
    }
    asm volatile("" ::: "memory");
  };

  // cell update + packed (2 units/dword) relaxed atomic h store
  auto cellstore = [&](const f32x4& aP, const f32x4& aQ,
                       unsigned* __restrict__ houtU, bool wrF){
    #pragma unroll
    for (int r = 0; r < 4; ++r){
      float v  = aP[r] + aQ[r] + bgv;
      float v1 = __shfl_xor(v, 1);
      float v2 = __shfl_xor(v, 2);
      float v3 = __shfl_xor(v, 3);
      auto pick = [&](int m)->float {
        return m == 0 ? v : (m == 1 ? v1 : (m == 2 ? v2 : v3));
      };
      float gi = pick(mygate);
      float gf = pick(mygate ^ 1);
      float gg = pick(mygate ^ 2);
      float go = pick(mygate ^ 3);
      float i_ = fsig(gi);
      float f_ = fsig(gf);
      float g_ = ftanh(gg);
      float o_ = fsig(go);
      float c  = f_ * cst[r] + i_ * g_;
      cst[r] = c;
      float h = o_ * ftanh(c);
      unsigned us = (unsigned)f2bf(h);
      unsigned up = __shfl_xor(us, 4);     // partner unit's bf16
      float    hp = __shfl_xor(h, 4);      // partner unit's fp32 (for wrF)
      if ((lj & 7) == 0){                  // lj in {0,8}: owns even unit, mygate==0
        int row   = m0 + mi * 16 + lk * 4 + r;
        int ueven = u0 + (wgrp << 2) + (lj >> 2);     // 0 or 2 offset, even
        size_t di = ((size_t)row * HD + ueven) >> 1;
        __hip_atomic_store(houtU + di, us | (up << 16),
                           __ATOMIC_RELAXED, __HIP_MEMORY_SCOPE_AGENT);
        if (wrF){
          H1f[(size_t)row * HD + ueven]     = h;
          H1f[(size_t)row * HD + ueven + 1] = hp;
        }
      }
    }
  };

  if (layer == 0){
    f32x4 accPre = {0.f, 0.f, 0.f, 0.f};
    halfK(Xp, 0, accPre, std::false_type{});            // x_0 projection
    for (int t = 0; t < TS; ++t){
      if (t > 0){
        if (wv == 0) pollwait(F0g, t, F1g, t - 15);     // peers done t-1; ring slot free
        __syncthreads();
      }
      f32x4 accPost = {0.f, 0.f, 0.f, 0.f};
      if (t > 0) halfK(h0r + (size_t)((t - 1) & 15) * SLAB, 64, accPost, std::true_type{});
      cellstore(accPre, accPost, (unsigned*)(h0r + (size_t)(t & 15) * SLAB), false);
      vdrain();                                         // h stores acked at coherence point
      __syncthreads();
      if (tid == 0)
        __hip_atomic_store(F0g + slice, t + 1, __ATOMIC_RELAXED, __HIP_MEMORY_SCOPE_AGENT);
      if (t + 1 < TS){
        accPre = (f32x4){0.f, 0.f, 0.f, 0.f};
        halfK(Xp + (size_t)(t + 1) * SLAB, 0, accPre, std::false_type{});
      }
    }
  } else {
    if (wv == 0) pollwait(F0g, 1, F0g, 1);              // h0[0] available
    __syncthreads();
    f32x4 accPre = {0.f, 0.f, 0.f, 0.f};
    halfK(h0r, 0, accPre, std::true_type{});            // h0[0] @ Wih1
    for (int t = 0; t < TS; ++t){
      const int tgtB = (t + 1 < TS) ? (t + 2) : 0;      // h0[t+1] availability for prefetch
      if (wv == 0) pollwait(F1g, t, F0g, tgtB);         // single merged poll per step
      __syncthreads();
      f32x4 accPost = {0.f, 0.f, 0.f, 0.f};
      if (t > 0) halfK(h1r + (size_t)((t - 1) & 1) * SLAB, 64, accPost, std::true_type{});
      cellstore(accPre, accPost, (unsigned*)(h1r + (size_t)(t & 1) * SLAB), t == TS - 1);
      vdrain();
      __syncthreads();
      if (tid == 0)
        __hip_atomic_store(F1g + slice, t + 1, __ATOMIC_RELAXED, __HIP_MEMORY_SCOPE_AGENT);
      if (t + 1 < TS){
        accPre = (f32x4){0.f, 0.f, 0.f, 0.f};
        halfK(h0r + (size_t)((t + 1) & 15) * SLAB, 0, accPre, std::true_type{});
      }
    }
  }
}

// out[b] = dot(h1_fwd[b], Wlin[0:512]) + dot(h1_rev[b], Wlin[512:1024]) + blin
__global__ void final_linear(const float* __restrict__ H1f, const float* __restrict__ Wlin,
                             const float* __restrict__ blin, float* __restrict__ out){
  int b = blockIdx.x, l = threadIdx.x;
  float s = 0.f;
  for (int j = l; j < HD; j += 64) s += H1f[(size_t)b * HD + j]        * Wlin[j];
  for (int j = l; j < HD; j += 64) s += H1f[(size_t)(NB + b) * HD + j] * Wlin[HD + j];
  #pragma unroll
  for (int off = 32; off; off >>= 1) s += __shfl_down(s, off);
  if (l == 0) out[b] = s + blin[0];
}

extern "C" void kernel_launch(void* const* d_in, const int* in_sizes, int n_in,
                              void* d_out, int out_size, void* d_ws, size_t ws_size,
                              hipStream_t stream)
{
  const float* text = (const float*)d_in[0];
  const float* Wih0 = (const float*)d_in[1];
  const float* Whh0 = (const float*)d_in[2];
  const float* bih0 = (const float*)d_in[3];
  const float* bhh0 = (const float*)d_in[4];
  const float* Wih1 = (const float*)d_in[5];
  const float* Whh1 = (const float*)d_in[6];
  const float* bih1 = (const float*)d_in[7];
  const float* bhh1 = (const float*)d_in[8];
  const float* Wlin = (const float*)d_in[9];
  const float* blin = (const float*)d_in[10];

  // ---- ws layout (~43 MiB) ----
  uint8_t* p = (uint8_t*)d_ws;
  unsigned short* Wc  = (unsigned short*)p; p += (size_t)2 * 2048 * 1024 * 2;  // 8 MiB
  float* bias         = (float*)p;          p += (size_t)2 * 2048 * 4;         // 16 KiB
  unsigned short* Xp  = (unsigned short*)p; p += (size_t)TS * SLAB * 2;        // 32 MiB
  unsigned short* h0r = (unsigned short*)p; p += (size_t)16 * SLAB * 2;        // 2 MiB ring
  unsigned short* h1r = (unsigned short*)p; p += (size_t)2 * SLAB * 2;         // 256 KiB ring
  float* H1f          = (float*)p;          p += (size_t)SLAB * 4;             // 256 KiB
  int* F              = (int*)p;            p += (size_t)256 * 4;              // 1 KiB flags

  // deterministic init every call: flags MUST be zero at kernel start
  hipMemsetAsync(F, 0, 256 * 4, stream);

  prep_w<<<8192, 256, 0, stream>>>(Wih0, Whh0, Wc);
  prep_w<<<8192, 256, 0, stream>>>(Wih1, Whh1, Wc + (size_t)2048 * 1024);
  prep_bias<<<8, 256, 0, stream>>>(bih0, bhh0, bias);
  prep_bias<<<8, 256, 0, stream>>>(bih1, bhh1, bias + 2048);
  pack_x<<<65536, 256, 0, stream>>>(text, Xp);

  hipFuncSetAttribute((const void*)lstm_persist,
                      hipFuncAttributeMaxDynamicSharedMemorySize, 131072);

  const unsigned short* XpA = Xp;
  const unsigned short* WcA = Wc;
  const float* biasA = bias;
  unsigned short* h0A = h0r;
  unsigned short* h1A = h1r;
  float* H1fA = H1f;
  int* FA = F;
  void* args[] = {(void*)&XpA, (void*)&WcA, (void*)&biasA,
                  (void*)&h0A, (void*)&h1A, (void*)&H1fA, (void*)&FA};
  hipLaunchCooperativeKernel((void*)lstm_persist, dim3(256), dim3(512),
                             args, 131072, stream);

  final_linear<<<NB, 64, 0, stream>>>(H1f, Wlin, blin, (float*)d_out);
}

// Round 6
// 3118.466 us; speedup vs baseline: 2.5811x; 2.5811x over previous
//
#include <hip/hip_runtime.h>
#include <stdint.h>
#include <math.h>

// ---- problem constants ----
constexpr int HD   = 512;    // hidden/embed dim
constexpr int TS   = 256;    // sequence length
constexpr int NB   = 64;     // batch per direction
constexpr int MBR  = 128;    // fwd+rev batched rows
constexpr int SLAB = MBR * HD;  // 65536 elements per h-slab

typedef __attribute__((ext_vector_type(8))) short bf16x8;
typedef __attribute__((ext_vector_type(4))) float f32x4;

__device__ __forceinline__ unsigned short f2bf(float f){
  union { float f; unsigned u; } v; v.f = f;
  unsigned r = v.u + 0x7fffu + ((v.u >> 16) & 1u);
  return (unsigned short)(r >> 16);
}
__device__ __forceinline__ float fsig(float x){ return 1.f / (1.f + __expf(-x)); }
__device__ __forceinline__ float ftanh(float x){ return 1.f - 2.f / (__expf(2.f * x) + 1.f); }
__device__ __forceinline__ void vdrain(){ asm volatile("s_waitcnt vmcnt(0)" ::: "memory"); }

// flag loads: sc0 = L1-bypass, served by local XCD L2 (fast local coherence);
// sc0 sc1 = bypass L1+L2, served at L3 (cross-XCD coherence)
__device__ __forceinline__ int ld_flag_sc0(const int* p){
  int v;
  asm volatile("global_load_dword %0, %1, off sc0\n\ts_waitcnt vmcnt(0)"
               : "=v"(v) : "v"(p) : "memory");
  return v;
}
__device__ __forceinline__ int ld_flag_sc1(const int* p){
  int v;
  asm volatile("global_load_dword %0, %1, off sc0 sc1\n\ts_waitcnt vmcnt(0)"
               : "=v"(v) : "v"(p) : "memory");
  return v;
}
__device__ __forceinline__ void st_sc1_b32(void* p, int v){
  asm volatile("global_store_dword %0, %1, off sc0 sc1" :: "v"(p), "v"(v) : "memory");
}

// 16 x 16B loads (one A-row of one K-half), single waitcnt. Contiguous 1KB.
#define LD16_DEF(NAME, FLAGS)                                                   \
__device__ __forceinline__ void NAME(const void* p, f32x4* r){                  \
  asm volatile(                                                                 \
    "global_load_dwordx4 %0,  %16, off " FLAGS "\n\t"                           \
    "global_load_dwordx4 %1,  %16, off offset:64 " FLAGS "\n\t"                 \
    "global_load_dwordx4 %2,  %16, off offset:128 " FLAGS "\n\t"                \
    "global_load_dwordx4 %3,  %16, off offset:192 " FLAGS "\n\t"                \
    "global_load_dwordx4 %4,  %16, off offset:256 " FLAGS "\n\t"                \
    "global_load_dwordx4 %5,  %16, off offset:320 " FLAGS "\n\t"                \
    "global_load_dwordx4 %6,  %16, off offset:384 " FLAGS "\n\t"                \
    "global_load_dwordx4 %7,  %16, off offset:448 " FLAGS "\n\t"                \
    "global_load_dwordx4 %8,  %16, off offset:512 " FLAGS "\n\t"                \
    "global_load_dwordx4 %9,  %16, off offset:576 " FLAGS "\n\t"                \
    "global_load_dwordx4 %10, %16, off offset:640 " FLAGS "\n\t"                \
    "global_load_dwordx4 %11, %16, off offset:704 " FLAGS "\n\t"                \
    "global_load_dwordx4 %12, %16, off offset:768 " FLAGS "\n\t"                \
    "global_load_dwordx4 %13, %16, off offset:832 " FLAGS "\n\t"                \
    "global_load_dwordx4 %14, %16, off offset:896 " FLAGS "\n\t"                \
    "global_load_dwordx4 %15, %16, off offset:960 " FLAGS "\n\t"                \
    "s_waitcnt vmcnt(0)"                                                        \
    : "=&v"(r[0]), "=&v"(r[1]), "=&v"(r[2]), "=&v"(r[3]),                       \
      "=&v"(r[4]), "=&v"(r[5]), "=&v"(r[6]), "=&v"(r[7]),                       \
      "=&v"(r[8]), "=&v"(r[9]), "=&v"(r[10]), "=&v"(r[11]),                     \
      "=&v"(r[12]), "=&v"(r[13]), "=&v"(r[14]), "=&v"(r[15])                    \
    : "v"(p) : "memory");                                                       \
}
LD16_DEF(ld16_sc0, "sc0")
LD16_DEF(ld16_sc1, "sc0 sc1")

// Xp[t][row][k] bf16: row<64: text[row][t][k]; row>=64: text[row-64][TS-1-t][k]
__global__ void pack_x(const float* __restrict__ text, unsigned short* __restrict__ Xp){
  int idx = blockIdx.x * 256 + threadIdx.x;   // TS*MBR*HD = 16,777,216
  int k   = idx & 511;
  int row = (idx >> 9) & 127;
  int t   = idx >> 16;
  int b   = row & 63;
  int tt  = (row < 64) ? t : (TS - 1 - t);
  Xp[idx] = f2bf(text[((size_t)b * TS + tt) * HD + k]);
}

// Persistent pipelined 2-layer LSTM, XCD-local recurrence sync.
// 256 WGs x 512 thr, 1 WG/CU (128KB LDS). Role via HW_REG_XCC_ID claim:
//   layer = xcd&1, grp = xcd>>1 (32 batch rows), slice = claim idx (16 units).
// Layer-local sync (same XCD, via L2): plain h stores + vmcnt drain + plain
// flag store; consumers poll sc0, read h via ld16_sc0. Cross-layer L0->L1:
// sc1 write-through copy h0x + per-step F0x flags (sc1), prefetched with
// 1-step slack. L1->L0 backpressure: coarse F1x flag every 8 steps.
__global__ __launch_bounds__(512, 1)
void lstm_persist(const unsigned short* __restrict__ Xp,
                  const float* __restrict__ Wih0, const float* __restrict__ Whh0,
                  const float* __restrict__ bih0, const float* __restrict__ bhh0,
                  const float* __restrict__ Wih1, const float* __restrict__ Whh1,
                  const float* __restrict__ bih1, const float* __restrict__ bhh1,
                  unsigned short* __restrict__ h0r,   // [4][128][512] local ring
                  unsigned short* __restrict__ h0x,   // [16][128][512] cross ring
                  unsigned short* __restrict__ h1r,   // [4][128][512] local ring
                  float* __restrict__ H1f,            // [128][512] final h1 fp32
                  int* __restrict__ F,                // 16 sets x [256][32] flags
                  unsigned* __restrict__ claim)       // [8] per-XCD claim counters
{
  extern __shared__ unsigned short Blds[];   // 64 cols x 1024 k, swizzled, 128 KB
  __shared__ int s_role;

  const int tid = threadIdx.x;
  if (tid == 0){
    unsigned xcc;
    asm volatile("s_getreg_b32 %0, hwreg(HW_REG_XCC_ID)" : "=s"(xcc));
    xcc &= 7u;
    unsigned idx = __hip_atomic_fetch_add(claim + xcc, 1u,
                     __ATOMIC_RELAXED, __HIP_MEMORY_SCOPE_AGENT);
    s_role = (int)((xcc << 5) | (idx & 31u));
  }
  __syncthreads();
  const int role  = s_role;
  const int xcd   = role >> 5;
  const int layer = xcd & 1;
  const int grp   = xcd >> 1;
  const int slice = role & 31;
  const int m0    = grp * 32;
  const int u0    = slice * 16;
  const int wv    = tid >> 6;
  const int l     = tid & 63;
  const int lj    = l & 15;
  const int lk    = l >> 4;
  const int wgrp  = wv & 3;
  const int mi    = wv >> 2;

  int* F0loc = F + (0 + grp) * (TS * 32);
  int* F1loc = F + (4 + grp) * (TS * 32);
  int* F0x   = F + (8 + grp) * (TS * 32);
  int* F1xg  = F + (12 + grp) * (TS * 32);   // coarse: idx t>>3

  // ---- one-time: stage weight slice into LDS (f32 -> bf16, swizzled) ----
  const float* Wihl = layer ? Wih1 : Wih0;
  const float* Whhl = layer ? Whh1 : Whh0;
  for (int it = tid; it < 64 * 128; it += 512){
    int c = it >> 7, kg = it & 127;
    int unit = u0 + ((c >> 4) << 2) + ((c & 15) >> 2);
    int gate = c & 3;
    const float* src = (kg < 64) ? (Wihl + (size_t)(gate * HD + unit) * HD + kg * 8)
                                 : (Whhl + (size_t)(gate * HD + unit) * HD + (kg - 64) * 8);
    float4 v0 = ((const float4*)src)[0];
    float4 v1 = ((const float4*)src)[1];
    bf16x8 w;
    w[0] = (short)f2bf(v0.x); w[1] = (short)f2bf(v0.y);
    w[2] = (short)f2bf(v0.z); w[3] = (short)f2bf(v0.w);
    w[4] = (short)f2bf(v1.x); w[5] = (short)f2bf(v1.y);
    w[6] = (short)f2bf(v1.z); w[7] = (short)f2bf(v1.w);
    *(bf16x8*)((char*)Blds + c * 2048 + ((kg ^ (c & 7)) << 4)) = w;
  }

  const int myunit = u0 + (wgrp << 2) + (lj >> 2);
  const int mygate = lj & 3;
  const float bgv  = (layer ? bih1 : bih0)[mygate * HD + myunit]
                   + (layer ? bhh1 : bhh0)[mygate * HD + myunit];
  const int aoff   = (m0 + mi * 16 + lj) * HD + lk * 8;   // A element offset
  const int cboff  = (wgrp * 16 + lj) * 2048;             // B col byte base
  const int swz    = lj & 7;

  float cst[4] = {0.f, 0.f, 0.f, 0.f};
  __syncthreads();   // weights staged

  auto ldsB = [&](int kg)->bf16x8 {
    return *(const bf16x8*)((const char*)Blds + cboff + ((kg ^ swz) << 4));
  };
  // wave-0 poll: lanes 0..31 watch pA[l]; lanes 32..63 watch pB[l-32]
  auto pollwait = [&](const int* pA, bool a1, const int* pB, bool b1){
    const int* fp = (l < 32) ? (pA + l) : (pB + (l - 32));
    const bool s1 = (l < 32) ? a1 : b1;
    for (;;){
      int v = s1 ? ld_flag_sc1(fp) : ld_flag_sc0(fp);
      if (__all(v != 0)) break;
      __builtin_amdgcn_s_sleep(1);
    }
  };
  // cell update; plain local h store; optional sc1 cross store; optional fp32
  auto cellstore = [&](const f32x4& aP, const f32x4& aQ,
                       unsigned short* __restrict__ hloc,
                       unsigned short* __restrict__ hx, bool wrF){
    #pragma unroll
    for (int r = 0; r < 4; ++r){
      float v  = aP[r] + aQ[r] + bgv;
      float v1 = __shfl_xor(v, 1);
      float v2 = __shfl_xor(v, 2);
      float v3 = __shfl_xor(v, 3);
      auto pick = [&](int m)->float {
        return m == 0 ? v : (m == 1 ? v1 : (m == 2 ? v2 : v3));
      };
      float gi = pick(mygate);
      float gf = pick(mygate ^ 1);
      float gg = pick(mygate ^ 2);
      float go = pick(mygate ^ 3);
      float i_ = fsig(gi);
      float f_ = fsig(gf);
      float g_ = ftanh(gg);
      float o_ = fsig(go);
      float c  = f_ * cst[r] + i_ * g_;
      cst[r] = c;
      float h  = o_ * ftanh(c);
      int row  = m0 + mi * 16 + lk * 4 + r;
      int hb   = (int)f2bf(h);
      int pb   = __shfl_xor(hb, 4);          // partner unit (myunit+1)
      if (mygate == 0){
        hloc[(size_t)row * HD + myunit] = (unsigned short)hb;
        if (wrF) H1f[(size_t)row * HD + myunit] = h;
      }
      if (hx && ((lj & 7) == 0))             // even units: packed dword, sc1
        st_sc1_b32((char*)hx + ((size_t)row * HD + myunit) * 2,
                   (hb & 0xffff) | (pb << 16));
    }
  };

  if (layer == 0){
    // ---- layer 0: local recurrence on this XCD; publishes h0x + F0x ----
    f32x4 accPre = {0.f, 0.f, 0.f, 0.f};
    #pragma unroll
    for (int kk = 0; kk < 16; ++kk)   // x_0 projection
      accPre = __builtin_amdgcn_mfma_f32_16x16x32_bf16(
                 *(const bf16x8*)(Xp + aoff + kk * 32), ldsB(kk * 4 + lk), accPre, 0, 0, 0);
    for (int t = 0; t < TS; ++t){
      if (t > 0){
        if (wv == 0){
          bool bp = (t >= 16) && ((t & 7) == 0);
          const int* pA = F0loc + (t - 1) * 32;
          const int* pB = bp ? (F1xg + ((t >> 3) - 2) * 32) : pA;
          pollwait(pA, false, pB, bp);
        }
        __syncthreads();
      }
      f32x4 accPost = {0.f, 0.f, 0.f, 0.f};
      if (t > 0){
        f32x4 raw[16];
        ld16_sc0(h0r + (size_t)((t - 1) & 3) * SLAB + aoff, raw);
        #pragma unroll
        for (int kk = 0; kk < 16; ++kk)
          accPost = __builtin_amdgcn_mfma_f32_16x16x32_bf16(
                      __builtin_bit_cast(bf16x8, raw[kk]), ldsB(64 + kk * 4 + lk),
                      accPost, 0, 0, 0);
      }
      cellstore(accPre, accPost, h0r + (size_t)(t & 3) * SLAB,
                h0x + (size_t)(t & 15) * SLAB, false);
      vdrain();          // local h in L2 + cross h0x acked at L3
      __syncthreads();
      if (tid == 0){
        *(volatile int*)(F0loc + t * 32 + slice) = 1;   // local release (L2)
        st_sc1_b32(F0x + t * 32 + slice, 1);            // cross release (L3)
      }
      if (t + 1 < TS){
        accPre = (f32x4){0.f, 0.f, 0.f, 0.f};
        #pragma unroll
        for (int kk = 0; kk < 16; ++kk)
          accPre = __builtin_amdgcn_mfma_f32_16x16x32_bf16(
                     *(const bf16x8*)(Xp + (size_t)(t + 1) * SLAB + aoff + kk * 32),
                     ldsB(kk * 4 + lk), accPre, 0, 0, 0);
      }
    }
  } else {
    // ---- layer 1: local recurrence; consumes h0x with 1-step lag ----
    f32x4 accPre = {0.f, 0.f, 0.f, 0.f};
    {
      if (wv == 0) pollwait(F0x, true, F0x, true);   // F0x[0]
      __syncthreads();
      f32x4 raw[16];
      ld16_sc1(h0x + aoff, raw);
      #pragma unroll
      for (int kk = 0; kk < 16; ++kk)
        accPre = __builtin_amdgcn_mfma_f32_16x16x32_bf16(
                   __builtin_bit_cast(bf16x8, raw[kk]), ldsB(kk * 4 + lk), accPre, 0, 0, 0);
    }
    for (int t = 0; t < TS; ++t){
      if (t > 0){
        if (wv == 0) pollwait(F1loc + (t - 1) * 32, false, F1loc + (t - 1) * 32, false);
        __syncthreads();
      }
      f32x4 accPost = {0.f, 0.f, 0.f, 0.f};
      if (t > 0){
        f32x4 raw[16];
        ld16_sc0(h1r + (size_t)((t - 1) & 3) * SLAB + aoff, raw);
        #pragma unroll
        for (int kk = 0; kk < 16; ++kk)
          accPost = __builtin_amdgcn_mfma_f32_16x16x32_bf16(
                      __builtin_bit_cast(bf16x8, raw[kk]), ldsB(64 + kk * 4 + lk),
                      accPost, 0, 0, 0);
      }
      cellstore(accPre, accPost, h1r + (size_t)(t & 3) * SLAB, nullptr, t == TS - 1);
      vdrain();
      __syncthreads();
      if (tid == 0){
        *(volatile int*)(F1loc + t * 32 + slice) = 1;           // local release
        if ((t & 7) == 7) st_sc1_b32(F1xg + (t >> 3) * 32 + slice, 1);  // progress
      }
      if (t + 1 < TS){
        if (wv == 0) pollwait(F0x + (t + 1) * 32, true, F0x + (t + 1) * 32, true);
        __syncthreads();
        accPre = (f32x4){0.f, 0.f, 0.f, 0.f};
        f32x4 raw[16];
        ld16_sc1(h0x + (size_t)((t + 1) & 15) * SLAB + aoff, raw);
        #pragma unroll
        for (int kk = 0; kk < 16; ++kk)
          accPre = __builtin_amdgcn_mfma_f32_16x16x32_bf16(
                     __builtin_bit_cast(bf16x8, raw[kk]), ldsB(kk * 4 + lk),
                     accPre, 0, 0, 0);
      }
    }
  }
}

// out[b] = dot(h1_fwd[b], Wlin[0:512]) + dot(h1_rev[b], Wlin[512:1024]) + blin
__global__ void final_linear(const float* __restrict__ H1f, const float* __restrict__ Wlin,
                             const float* __restrict__ blin, float* __restrict__ out){
  int b = blockIdx.x, l = threadIdx.x;
  float s = 0.f;
  for (int j = l; j < HD; j += 64) s += H1f[(size_t)b * HD + j]        * Wlin[j];
  for (int j = l; j < HD; j += 64) s += H1f[(size_t)(NB + b) * HD + j] * Wlin[HD + j];
  #pragma unroll
  for (int off = 32; off; off >>= 1) s += __shfl_down(s, off);
  if (l == 0) out[b] = s + blin[0];
}

extern "C" void kernel_launch(void* const* d_in, const int* in_sizes, int n_in,
                              void* d_out, int out_size, void* d_ws, size_t ws_size,
                              hipStream_t stream)
{
  const float* text = (const float*)d_in[0];
  const float* Wih0 = (const float*)d_in[1];
  const float* Whh0 = (const float*)d_in[2];
  const float* bih0 = (const float*)d_in[3];
  const float* bhh0 = (const float*)d_in[4];
  const float* Wih1 = (const float*)d_in[5];
  const float* Whh1 = (const float*)d_in[6];
  const float* bih1 = (const float*)d_in[7];
  const float* bhh1 = (const float*)d_in[8];
  const float* Wlin = (const float*)d_in[9];
  const float* blin = (const float*)d_in[10];

  // ---- ws layout (~36 MiB) ----
  uint8_t* p = (uint8_t*)d_ws;
  unsigned short* Xp  = (unsigned short*)p; p += (size_t)TS * SLAB * 2;   // 32 MiB
  unsigned short* h0r = (unsigned short*)p; p += (size_t)4 * SLAB * 2;    // 512 KiB
  unsigned short* h0x = (unsigned short*)p; p += (size_t)16 * SLAB * 2;   // 2 MiB
  unsigned short* h1r = (unsigned short*)p; p += (size_t)4 * SLAB * 2;    // 512 KiB
  float* H1f          = (float*)p;          p += (size_t)SLAB * 4;        // 256 KiB
  int* F              = (int*)p;            p += (size_t)16 * TS * 32 * 4;// 512 KiB
  unsigned* claim     = (unsigned*)p;       p += 256;

  // deterministic init: flags + claim counters zero at kernel start
  hipMemsetAsync(F, 0, (size_t)16 * TS * 32 * 4 + 256, stream);

  pack_x<<<65536, 256, 0, stream>>>(text, Xp);

  hipFuncSetAttribute((const void*)lstm_persist,
                      hipFuncAttributeMaxDynamicSharedMemorySize, 131072);

  const unsigned short* XpA = Xp;
  unsigned short* h0A = h0r; unsigned short* hxA = h0x; unsigned short* h1A = h1r;
  float* H1fA = H1f; int* FA = F; unsigned* clA = claim;
  void* args[] = {(void*)&XpA,
                  (void*)&Wih0, (void*)&Whh0, (void*)&bih0, (void*)&bhh0,
                  (void*)&Wih1, (void*)&Whh1, (void*)&bih1, (void*)&bhh1,
                  (void*)&h0A, (void*)&hxA, (void*)&h1A, (void*)&H1fA,
                  (void*)&FA, (void*)&clA};
  hipLaunchCooperativeKernel((void*)lstm_persist, dim3(256), dim3(512),
                             args, 131072, stream);

  final_linear<<<NB, 64, 0, stream>>>(H1f, Wlin, blin, (float*)d_out);
}